// Round 8
// baseline (69.084 us; speedup 1.0000x reference)
//
#include <hip/hip_runtime.h>
#include <hip/hip_bf16.h>

#define HW 9216
#define CDIM 128
#define ROWS_W 64                   // rows per wave (2 x 32-row fragments)
#define NCH 12                      // 32-col chains per wave
#define COLS_W (NCH * 32)           // 384
#define GRID_I (HW / (ROWS_W * 4))  // 36 (4 waves per block)
#define GRID_J (HW / COLS_W)        // 24
#define NPART (GRID_I * GRID_J * 4) // 3456 per-wave partial pairs

using bf16 = __hip_bfloat16;
typedef __attribute__((ext_vector_type(16))) float f32x16;
typedef __attribute__((ext_vector_type(8))) short s16x8;

// exp(d/0.04) = exp2(d * log2(e)/0.04); scale folded into feat1 at prep time
#define EXP_SCALE 36.067376022224085f

#if __has_builtin(__builtin_amdgcn_exp2f)
#define FEXP2(x) __builtin_amdgcn_exp2f(x)
#else
#define FEXP2(x) exp2f(x)
#endif

// ---------------------------------------------------------------------------
// Kernel 1: x[b] [C][HW] f32 -> feat[b] [HW][C] bf16 (feat1 pre-scaled).
// Coalesced reads AND writes (no permutation). grid=(HW/64, C/64, 2).
// ---------------------------------------------------------------------------
__global__ __launch_bounds__(256) void prep_kernel(const float* __restrict__ x,
                                                   bf16* __restrict__ feat) {
    __shared__ float tile[64][65];
    const float* xs = x + (size_t)blockIdx.z * CDIM * HW;
    bf16* fs = feat + (size_t)blockIdx.z * HW * CDIM;
    float scale = (blockIdx.z == 0) ? EXP_SCALE : 1.0f;

    int p0 = blockIdx.x * 64;
    int c0 = blockIdx.y * 64;
    int t  = threadIdx.x;

    int pc = t & 63;
    int cr = t >> 6;
#pragma unroll
    for (int i = 0; i < 16; ++i) {
        int cl = cr + i * 4;
        tile[cl][pc] = xs[(size_t)(c0 + cl) * HW + p0 + pc];
    }
    __syncthreads();

    int cc = t & 63;
    int pr = t >> 6;
#pragma unroll
    for (int i = 0; i < 16; ++i) {
        int pl = pr + i * 4;
        fs[(size_t)(p0 + pl) * CDIM + c0 + cc] = __float2bfloat16(tile[cc][pl] * scale);
    }
}

// ---------------------------------------------------------------------------
// Kernel 2: barrier-free, LDS-free. Wave = 64 rows x 384 cols, independent.
// A frags + 2-bit-packed row labels register-resident. Per 32-col chain:
// 8 B-frags from L2 (rolling reload during MFMA = prefetch w/o extra regs),
// 16x mfma_f32_32x32x16_bf16 (2 indep chains), bit-mask epilogue.
// grid = (36, 24), block = 256 (4 independent waves). Per-wave partials.
// ---------------------------------------------------------------------------
__global__ __launch_bounds__(256, 3) void simsum_kernel(const bf16* __restrict__ feat1,
                                                        const bf16* __restrict__ feat2,
                                                        const int* __restrict__ label,
                                                        float* __restrict__ partials) {
    int t    = threadIdx.x;
    int w    = t >> 6;
    int lane = t & 63;
    int cl   = lane & 31;        // fragment row/col lane index
    int hi   = lane >> 5;        // k-half select

    int r0 = (blockIdx.x * 4 + w) * ROWS_W;
    int c0 = blockIdx.y * COLS_W;

    // A fragments (pre-scaled feat1): af[m][s], lane row = cl, k = s*16+hi*8
    s16x8 af[2][8];
#pragma unroll
    for (int m = 0; m < 2; ++m) {
        const bf16* ar = &feat1[(size_t)(r0 + m * 32 + cl) * CDIM + hi * 8];
#pragma unroll
        for (int s = 0; s < 8; ++s)
            af[m][s] = *(const s16x8*)(ar + s * 16);
    }

    // 2-bit-packed row labels per 32-row fragment:
    // C row r (0..15) = (r&3) + 8*(r>>2) + 4*hi  ->  label at base + 8q + j
    unsigned pk[2];
#pragma unroll
    for (int m = 0; m < 2; ++m) {
        unsigned p = 0;
        int base = r0 + m * 32 + 4 * hi;
#pragma unroll
        for (int q = 0; q < 4; ++q) {
            int4 v = *(const int4*)(&label[base + 8 * q]);
            p |= ((unsigned)v.x) << (8 * q);
            p |= ((unsigned)v.y) << (8 * q + 2);
            p |= ((unsigned)v.z) << (8 * q + 4);
            p |= ((unsigned)v.w) << (8 * q + 6);
        }
        pk[m] = p;
    }

    const int* lab2 = label + HW;
    float tot = 0.f, pos = 0.f;

    s16x8 bfv[8];
    // prologue: load chain 0's B fragments
    {
        const bf16* br = &feat2[(size_t)(c0 + cl) * CDIM + hi * 8];
#pragma unroll
        for (int s = 0; s < 8; ++s)
            bfv[s] = *(const s16x8*)(br + s * 16);
    }

    // one chain: 16 MFMA + (optional) rolling reload of next chain + epilogue
    auto chain = [&](int ch, bool reload) {
        int jc = c0 + ch * 32;
        int g2 = lab2[jc + cl];                       // per-lane column label
        const bf16* bnext = &feat2[(size_t)(jc + 32 + cl) * CDIM + hi * 8];

        f32x16 a0 = {}, a1 = {};
#pragma unroll
        for (int s = 0; s < 8; ++s) {
            s16x8 b = bfv[s];
            a0 = __builtin_amdgcn_mfma_f32_32x32x16_bf16(af[0][s], b, a0, 0, 0, 0);
            a1 = __builtin_amdgcn_mfma_f32_32x32x16_bf16(af[1][s], b, a1, 0, 0, 0);
            if (reload) bfv[s] = *(const s16x8*)(bnext + s * 16);  // next chain
        }

        // mask bits: z bit(2r) = (rowlabel_r == g2)
        unsigned g2r = (unsigned)g2 * 0x55555555u;
        unsigned d0 = pk[0] ^ g2r, d1 = pk[1] ^ g2r;
        unsigned z0 = ~(d0 | (d0 >> 1)) & 0x55555555u;
        unsigned z1 = ~(d1 | (d1 >> 1)) & 0x55555555u;

#pragma unroll
        for (int r = 0; r < 16; ++r) {
            float e0 = FEXP2(a0[r]);
            tot += e0;
            pos = fmaf((float)((z0 >> (2 * r)) & 1u), e0, pos);
            float e1 = FEXP2(a1[r]);
            tot += e1;
            pos = fmaf((float)((z1 >> (2 * r)) & 1u), e1, pos);
        }
    };

#pragma unroll
    for (int ch = 0; ch < NCH - 1; ++ch)
        chain(ch, true);
    chain(NCH - 1, false);

    // wave reduce -> per-wave partial
#pragma unroll
    for (int off = 32; off; off >>= 1) {
        tot += __shfl_down(tot, off);
        pos += __shfl_down(pos, off);
    }
    if (lane == 0) {
        int wid = (blockIdx.y * GRID_I + blockIdx.x) * 4 + w;
        partials[wid * 2]     = tot;
        partials[wid * 2 + 1] = pos;
    }
}

// ---------------------------------------------------------------------------
// Kernel 3: reduce partial pairs, loss = -log(pos/tot)/hw^2
// ---------------------------------------------------------------------------
__global__ __launch_bounds__(256) void finalize_kernel(const float* __restrict__ partials,
                                                       float* __restrict__ out) {
    double tot = 0.0, pos = 0.0;
    int t = threadIdx.x;
    for (int i = t; i < NPART; i += 256) {
        tot += (double)partials[i * 2];
        pos += (double)partials[i * 2 + 1];
    }
#pragma unroll
    for (int off = 32; off; off >>= 1) {
        tot += __shfl_down(tot, off);
        pos += __shfl_down(pos, off);
    }
    __shared__ double rt[4], rp[4];
    int w = t >> 6, lane = t & 63;
    if (lane == 0) { rt[w] = tot; rp[w] = pos; }
    __syncthreads();
    if (t == 0) {
        double T = rt[0] + rt[1] + rt[2] + rt[3];
        double P = rp[0] + rp[1] + rp[2] + rp[3];
        double hw2 = (double)HW * (double)HW;
        out[0] = (float)(-log(P / T) / hw2);
    }
}

extern "C" void kernel_launch(void* const* d_in, const int* in_sizes, int n_in,
                              void* d_out, int out_size, void* d_ws, size_t ws_size,
                              hipStream_t stream) {
    const float* x     = (const float*)d_in[0];   // (4,128,96,96) f32; only b=0,1 used
    const int*   label = (const int*)d_in[1];     // (4,1,96,96) i32; only b=0,1 used
    float*       out   = (float*)d_out;

    bf16*  feat  = (bf16*)d_ws;                       // feat1 (pre-scaled), feat2
    float* parts = (float*)((char*)d_ws + 2 * (size_t)HW * CDIM * sizeof(bf16));

    dim3 g1(HW / 64, CDIM / 64, 2);
    prep_kernel<<<g1, 256, 0, stream>>>(x, feat);

    dim3 g2(GRID_I, GRID_J);
    simsum_kernel<<<g2, 256, 0, stream>>>(feat, feat + (size_t)HW * CDIM, label, parts);

    finalize_kernel<<<1, 256, 0, stream>>>(parts, out);
}

// Round 9
// 47.242 us; speedup vs baseline: 1.4623x; 1.4623x over previous
//
#include <hip/hip_runtime.h>
#include <hip/hip_bf16.h>

#define HW 9216
#define CDIM 128
#define ROWS_W 64                   // rows per wave (2 x 32-row fragments)
#define NCH 12                      // 32-col chains per wave
#define COLS_W (NCH * 32)           // 384
#define GRID_I (HW / (ROWS_W * 4))  // 36 (4 waves per block)
#define GRID_J (HW / COLS_W)        // 24
#define NPART (GRID_I * GRID_J * 4) // 3456 per-wave partial pairs

using bf16 = __hip_bfloat16;
typedef __attribute__((ext_vector_type(16))) float f32x16;
typedef __attribute__((ext_vector_type(8))) short s16x8;

// exp(d/0.04) = exp2(d * log2(e)/0.04); scale folded into feat1 at prep time
#define EXP_SCALE 36.067376022224085f

#if __has_builtin(__builtin_amdgcn_exp2f)
#define FEXP2(x) __builtin_amdgcn_exp2f(x)
#else
#define FEXP2(x) exp2f(x)
#endif

// ---------------------------------------------------------------------------
// Kernel 1: x[b] [C][HW] f32 -> frag[b] in MFMA fragment layout:
//   frag[jblock][s][lane][e]  (jblock = row/32, s = k-step 0..7,
//   lane = hi*32 + row%32 with hi = (col/8)%2, e = col%8)
// so a wave's fragment load = ONE coalesced 1KB read at base + s*1024.
// feat1 (z=0) pre-scaled by EXP_SCALE. grid=(HW/64, C/64, 2), block=256.
// ---------------------------------------------------------------------------
__global__ __launch_bounds__(256) void prep_kernel(const float* __restrict__ x,
                                                   bf16* __restrict__ frag) {
    __shared__ float tile[64][65];
    const float* xs = x + (size_t)blockIdx.z * CDIM * HW;
    bf16* fs = frag + (size_t)blockIdx.z * HW * CDIM;
    float scale = (blockIdx.z == 0) ? EXP_SCALE : 1.0f;

    int p0 = blockIdx.x * 64;
    int c0 = blockIdx.y * 64;
    int t  = threadIdx.x;

    // coalesced read + LDS transpose (tile[col_local][row_local])
    int pc = t & 63;
    int cr = t >> 6;
#pragma unroll
    for (int i = 0; i < 16; ++i) {
        int clc = cr + i * 4;
        tile[clc][pc] = xs[(size_t)(c0 + clc) * HW + p0 + pc];
    }
    __syncthreads();

    // write fragment chunks: thread -> (col-chunk b, lane-in-32 clw), 2 rows-halves
    int clw = t & 31;            // row % 32
    int b   = t >> 5;            // 0..7 col-chunk of 8
    int sF  = c0 / 16 + (b >> 1);
    int hiF = b & 1;
#pragma unroll
    for (int q = 0; q < 2; ++q) {
        int jblock = p0 / 32 + q;
        int prow   = clw + 32 * q;     // row_local
        s16x8 v;
#pragma unroll
        for (int j = 0; j < 8; ++j) {
            __hip_bfloat16 h = __float2bfloat16(tile[8 * b + j][prow] * scale);
            v[j] = *reinterpret_cast<short*>(&h);
        }
        // chunk index = (jblock*8 + s)*64 + hi*32 + clw ; 8 bf16 per chunk
        *(s16x8*)(&fs[(size_t)(((jblock * 8 + sF) * 64) + hiF * 32 + clw) * 8]) = v;
    }
}

// ---------------------------------------------------------------------------
// Kernel 2: barrier-free, LDS-free, all loads coalesced via fragment layout.
// Wave = 64 rows x 384 cols. A frags (2 blocks x 8 steps) + packed row labels
// register-resident; per 32-col chain: 8 x 1KB coalesced B loads (rolling
// reload during MFMA), 16x mfma_f32_32x32x16_bf16, bit-mask epilogue.
// grid = (36, 24), block = 256 (4 independent waves share B via L1/L2).
// ---------------------------------------------------------------------------
__global__ __launch_bounds__(256, 3) void simsum_kernel(const bf16* __restrict__ frag1,
                                                        const bf16* __restrict__ frag2,
                                                        const int* __restrict__ label,
                                                        float* __restrict__ partials) {
    int t    = threadIdx.x;
    int w    = t >> 6;
    int lane = t & 63;
    int cl   = lane & 31;

    int r0 = (blockIdx.x * 4 + w) * ROWS_W;
    int c0 = blockIdx.y * COLS_W;
    int jb0 = c0 / 32;               // first column block index

    const s16x8* F1 = ((const s16x8*)frag1) + lane;   // stride 64 chunks per (jblock,s)
    const s16x8* F2 = ((const s16x8*)frag2) + lane;

    // A fragments: af[m][s] -- one coalesced 1KB load each
    s16x8 af[2][8];
#pragma unroll
    for (int m = 0; m < 2; ++m)
#pragma unroll
        for (int s = 0; s < 8; ++s)
            af[m][s] = F1[(size_t)((r0 / 32 + m) * 8 + s) * 64];

    // 2-bit-packed row labels per 32-row fragment:
    // C reg r (0..15) -> row r0 + m*32 + (r&3) + 8*(r>>2) + 4*hi ; bit 2r
    int hi = lane >> 5;
    unsigned pk[2];
#pragma unroll
    for (int m = 0; m < 2; ++m) {
        unsigned p = 0;
        int base = r0 + m * 32 + 4 * hi;
#pragma unroll
        for (int q = 0; q < 4; ++q) {
            int4 v = *(const int4*)(&label[base + 8 * q]);
            p |= ((unsigned)v.x) << (8 * q);
            p |= ((unsigned)v.y) << (8 * q + 2);
            p |= ((unsigned)v.z) << (8 * q + 4);
            p |= ((unsigned)v.w) << (8 * q + 6);
        }
        pk[m] = p;
    }

    const int* lab2 = label + HW;
    float tot = 0.f, pos = 0.f;

    s16x8 bfv[8];
#pragma unroll
    for (int s = 0; s < 8; ++s)       // chain 0 prologue
        bfv[s] = F2[(size_t)(jb0 * 8 + s) * 64];

    auto chain = [&](int ch, bool reload) {
        int jblk = jb0 + ch;
        int g2 = lab2[jblk * 32 + cl];               // per-lane column label
        const s16x8* bnext = F2 + (size_t)((jblk + 1) * 8) * 64;

        f32x16 a0 = {}, a1 = {};
#pragma unroll
        for (int s = 0; s < 8; ++s) {
            s16x8 bq = bfv[s];
            a0 = __builtin_amdgcn_mfma_f32_32x32x16_bf16(af[0][s], bq, a0, 0, 0, 0);
            a1 = __builtin_amdgcn_mfma_f32_32x32x16_bf16(af[1][s], bq, a1, 0, 0, 0);
            if (reload) bfv[s] = bnext[(size_t)s * 64];   // next chain, coalesced
        }

        // mask bits: z bit(2r) = (rowlabel_r == g2)
        unsigned g2r = (unsigned)g2 * 0x55555555u;
        unsigned d0 = pk[0] ^ g2r, d1 = pk[1] ^ g2r;
        unsigned z0 = ~(d0 | (d0 >> 1)) & 0x55555555u;
        unsigned z1 = ~(d1 | (d1 >> 1)) & 0x55555555u;

#pragma unroll
        for (int r = 0; r < 16; ++r) {
            float e0 = FEXP2(a0[r]);
            tot += e0;
            pos = fmaf((float)((z0 >> (2 * r)) & 1u), e0, pos);
            float e1 = FEXP2(a1[r]);
            tot += e1;
            pos = fmaf((float)((z1 >> (2 * r)) & 1u), e1, pos);
        }
    };

#pragma unroll
    for (int ch = 0; ch < NCH - 1; ++ch)
        chain(ch, true);
    chain(NCH - 1, false);

    // wave reduce -> per-wave partial
#pragma unroll
    for (int off = 32; off; off >>= 1) {
        tot += __shfl_down(tot, off);
        pos += __shfl_down(pos, off);
    }
    if (lane == 0) {
        int wid = (blockIdx.y * GRID_I + blockIdx.x) * 4 + w;
        partials[wid * 2]     = tot;
        partials[wid * 2 + 1] = pos;
    }
}

// ---------------------------------------------------------------------------
// Kernel 3: reduce partial pairs, loss = -log(pos/tot)/hw^2
// ---------------------------------------------------------------------------
__global__ __launch_bounds__(256) void finalize_kernel(const float* __restrict__ partials,
                                                       float* __restrict__ out) {
    double tot = 0.0, pos = 0.0;
    int t = threadIdx.x;
    for (int i = t; i < NPART; i += 256) {
        tot += (double)partials[i * 2];
        pos += (double)partials[i * 2 + 1];
    }
#pragma unroll
    for (int off = 32; off; off >>= 1) {
        tot += __shfl_down(tot, off);
        pos += __shfl_down(pos, off);
    }
    __shared__ double rt[4], rp[4];
    int w = t >> 6, lane = t & 63;
    if (lane == 0) { rt[w] = tot; rp[w] = pos; }
    __syncthreads();
    if (t == 0) {
        double T = rt[0] + rt[1] + rt[2] + rt[3];
        double P = rp[0] + rp[1] + rp[2] + rp[3];
        double hw2 = (double)HW * (double)HW;
        out[0] = (float)(-log(P / T) / hw2);
    }
}

extern "C" void kernel_launch(void* const* d_in, const int* in_sizes, int n_in,
                              void* d_out, int out_size, void* d_ws, size_t ws_size,
                              hipStream_t stream) {
    const float* x     = (const float*)d_in[0];   // (4,128,96,96) f32; only b=0,1 used
    const int*   label = (const int*)d_in[1];     // (4,1,96,96) i32; only b=0,1 used
    float*       out   = (float*)d_out;

    bf16*  frag  = (bf16*)d_ws;                       // frag1 (pre-scaled), frag2
    float* parts = (float*)((char*)d_ws + 2 * (size_t)HW * CDIM * sizeof(bf16));

    dim3 g1(HW / 64, CDIM / 64, 2);
    prep_kernel<<<g1, 256, 0, stream>>>(x, frag);

    dim3 g2(GRID_I, GRID_J);
    simsum_kernel<<<g2, 256, 0, stream>>>(frag, frag + (size_t)HW * CDIM, label, parts);

    finalize_kernel<<<1, 256, 0, stream>>>(parts, out);
}

// Round 10
// 47.006 us; speedup vs baseline: 1.4697x; 1.0050x over previous
//
#include <hip/hip_runtime.h>
#include <hip/hip_bf16.h>

#define HW 9216
#define CDIM 128
#define ROWS_W 64                   // rows per wave (4 x 16-row m-frags)
#define NCH 12                      // 16-col chains per wave
#define COLS_W (NCH * 16)           // 192
#define GRID_I (HW / (ROWS_W * 4))  // 36 (4 waves per block, 256 rows/block)
#define GRID_J (HW / COLS_W)        // 48
#define GRID_T (GRID_I * GRID_J)    // 1728 blocks (mult of 8 -> bijective swizzle)
#define NPART (GRID_T * 4)          // 6912 per-wave partial pairs

using bf16 = __hip_bfloat16;
typedef __attribute__((ext_vector_type(4))) float f32x4;
typedef __attribute__((ext_vector_type(8))) short s16x8;

// exp(d/0.04) = exp2(d * log2(e)/0.04); scale folded into feat1 at prep time
#define EXP_SCALE 36.067376022224085f

#if __has_builtin(__builtin_amdgcn_exp2f)
#define FEXP2(x) __builtin_amdgcn_exp2f(x)
#else
#define FEXP2(x) exp2f(x)
#endif

// ---------------------------------------------------------------------------
// Kernel 1: x[b] [C][HW] f32 -> frag[b] in 16x16x32 MFMA fragment layout:
//   chunk[(iblock16*4 + ks)*64 + kg*16 + row16] = 8 bf16 {k = ks*32+kg*8+e}
// so a wave's A/B fragment load is ONE coalesced 1KB read (base + ks*1KB).
// feat1 (z=0) pre-scaled by EXP_SCALE. grid=(HW/64, CDIM/64, 2), block=256.
// ---------------------------------------------------------------------------
__global__ __launch_bounds__(256) void prep_kernel(const float* __restrict__ x,
                                                   bf16* __restrict__ frag) {
    __shared__ float tile[64][65];   // [chan_local][pos_local]
    const float* xs = x + (size_t)blockIdx.z * CDIM * HW;
    bf16* fs = frag + (size_t)blockIdx.z * HW * CDIM;
    float scale = (blockIdx.z == 0) ? EXP_SCALE : 1.0f;

    int p0 = blockIdx.x * 64;
    int c0 = blockIdx.y * 64;
    int t  = threadIdx.x;

    // coalesced read: 64 positions per row of 64 channels
    int pc = t & 63;
    int cr = t >> 6;
#pragma unroll
    for (int i = 0; i < 16; ++i) {
        int clc = cr + i * 4;
        tile[clc][pc] = xs[(size_t)(c0 + clc) * HW + p0 + pc];
    }
    __syncthreads();

    // 512 16B-chunks per (64pos x 64chan) tile; 2 per thread, coalesced writes
#pragma unroll
    for (int q = 0; q < 2; ++q) {
        int ch   = q * 256 + t;
        int row  = ch & 15;              // row within 16-block
        int kgq  = (ch >> 4) & 3;        // k-subgroup
        int ksl  = (ch >> 6) & 1;        // local ks (window covers 2)
        int ib   = (ch >> 7) & 3;        // 16-row block within 64-pos tile
        s16x8 v;
#pragma unroll
        for (int e = 0; e < 8; ++e) {
            __hip_bfloat16 h = __float2bfloat16(tile[ksl * 32 + kgq * 8 + e][ib * 16 + row] * scale);
            v[e] = *reinterpret_cast<short*>(&h);
        }
        size_t chunk = ((size_t)(p0 / 16 + ib) * 4 + (c0 / 32 + ksl)) * 64 + kgq * 16 + row;
        *(s16x8*)(&fs[chunk * 8]) = v;
    }
}

// ---------------------------------------------------------------------------
// Kernel 2: barrier-free, LDS-free, all fragment loads coalesced.
// Wave = 64 rows x 192 cols. af[4m][4ks] (64 VGPR) + 2-bit packed row labels
// resident; per 16-col chain: 4 x 1KB B loads (rolling reload at last use),
// 16x mfma_f32_16x16x32_bf16, bit-mask epilogue. 4 waves/block share B via
// L1; XCD-swizzled 1-D grid groups j-windows per XCD L2.
// grid = 1728, block = 256, 4 waves/SIMD via launch_bounds.
// ---------------------------------------------------------------------------
__global__ __launch_bounds__(256, 4) void simsum_kernel(const bf16* __restrict__ frag1,
                                                        const bf16* __restrict__ frag2,
                                                        const int* __restrict__ label,
                                                        float* __restrict__ partials) {
    int t    = threadIdx.x;
    int w    = t >> 6;
    int lane = t & 63;
    int lr   = lane & 15;        // fragment row/col lane index
    int kg   = lane >> 4;        // k-subgroup

    // bijective XCD swizzle: XCD g owns contiguous j-window range
    int orig = blockIdx.x;
    int wg   = (orig & 7) * (GRID_T / 8) + (orig >> 3);
    int jw   = wg / GRID_I;
    int iw   = wg % GRID_I;

    int r0 = iw * (ROWS_W * 4) + w * ROWS_W;   // this wave's 64 rows
    int c0 = jw * COLS_W;
    int jb0 = c0 / 16;                         // first 16-col block index

    const s16x8* F1 = ((const s16x8*)frag1) + lane;
    const s16x8* F2 = ((const s16x8*)frag2) + lane;

    // A fragments: af[m][ks], one coalesced 1KB load each
    s16x8 af[4][4];
#pragma unroll
    for (int m = 0; m < 4; ++m)
#pragma unroll
        for (int ks = 0; ks < 4; ++ks)
            af[m][ks] = F1[(size_t)((r0 / 16 + m) * 4 + ks) * 64];

    // 2-bit packed row labels: C reg r of m-frag -> row r0 + m*16 + kg*4 + r
    unsigned pk = 0;
#pragma unroll
    for (int m = 0; m < 4; ++m) {
        int4 v = *(const int4*)(&label[r0 + m * 16 + kg * 4]);
        unsigned b = (unsigned)v.x | ((unsigned)v.y << 2) |
                     ((unsigned)v.z << 4) | ((unsigned)v.w << 6);
        pk |= b << (8 * m);
    }

    const int* lab2 = label + HW;
    float tot = 0.f, pos = 0.f;

    s16x8 bf[4];
#pragma unroll
    for (int ks = 0; ks < 4; ++ks)    // chain 0 prologue
        bf[ks] = F2[(size_t)(jb0 * 4 + ks) * 64];

#pragma unroll
    for (int ch = 0; ch < NCH; ++ch) {
        int g2 = lab2[c0 + ch * 16 + lr];            // per-lane column label
        unsigned d = pk ^ ((unsigned)g2 * 0x55555555u);
        unsigned z = ~(d | (d >> 1)) & 0x55555555u;  // bit 2*(m*4+r) = match

        int nb = (ch + 1 < NCH) ? (ch + 1) : 0;      // folds at compile time
        const s16x8* bnext = F2 + (size_t)((jb0 + nb) * 4) * 64;

        f32x4 acc[4] = {};
#pragma unroll
        for (int ks = 0; ks < 4; ++ks) {
            s16x8 b = bf[ks];
#pragma unroll
            for (int m = 0; m < 4; ++m)
                acc[m] = __builtin_amdgcn_mfma_f32_16x16x32_bf16(af[m][ks], b, acc[m], 0, 0, 0);
            bf[ks] = bnext[(size_t)ks * 64];         // reload at last use
        }

        // epilogue: exp + masked/total accumulate
#pragma unroll
        for (int m = 0; m < 4; ++m) {
#pragma unroll
            for (int r = 0; r < 4; ++r) {
                float e = FEXP2(acc[m][r]);
                tot += e;
                pos += ((z >> (2 * (m * 4 + r))) & 1u) ? e : 0.f;
            }
        }
    }

    // wave reduce -> per-wave partial
#pragma unroll
    for (int off = 32; off; off >>= 1) {
        tot += __shfl_down(tot, off);
        pos += __shfl_down(pos, off);
    }
    if (lane == 0) {
        int wid = orig * 4 + w;
        partials[wid * 2]     = tot;
        partials[wid * 2 + 1] = pos;
    }
}

// ---------------------------------------------------------------------------
// Kernel 3: reduce partial pairs, loss = -log(pos/tot)/hw^2
// ---------------------------------------------------------------------------
__global__ __launch_bounds__(256) void finalize_kernel(const float* __restrict__ partials,
                                                       float* __restrict__ out) {
    double tot = 0.0, pos = 0.0;
    int t = threadIdx.x;
    for (int i = t; i < NPART; i += 256) {
        tot += (double)partials[i * 2];
        pos += (double)partials[i * 2 + 1];
    }
#pragma unroll
    for (int off = 32; off; off >>= 1) {
        tot += __shfl_down(tot, off);
        pos += __shfl_down(pos, off);
    }
    __shared__ double rt[4], rp[4];
    int w = t >> 6, lane = t & 63;
    if (lane == 0) { rt[w] = tot; rp[w] = pos; }
    __syncthreads();
    if (t == 0) {
        double T = rt[0] + rt[1] + rt[2] + rt[3];
        double P = rp[0] + rp[1] + rp[2] + rp[3];
        double hw2 = (double)HW * (double)HW;
        out[0] = (float)(-log(P / T) / hw2);
    }
}

extern "C" void kernel_launch(void* const* d_in, const int* in_sizes, int n_in,
                              void* d_out, int out_size, void* d_ws, size_t ws_size,
                              hipStream_t stream) {
    const float* x     = (const float*)d_in[0];   // (4,128,96,96) f32; only b=0,1 used
    const int*   label = (const int*)d_in[1];     // (4,1,96,96) i32; only b=0,1 used
    float*       out   = (float*)d_out;

    bf16*  frag  = (bf16*)d_ws;                       // frag1 (pre-scaled), frag2
    float* parts = (float*)((char*)d_ws + 2 * (size_t)HW * CDIM * sizeof(bf16));

    dim3 g1(HW / 64, CDIM / 64, 2);
    prep_kernel<<<g1, 256, 0, stream>>>(x, frag);

    simsum_kernel<<<GRID_T, 256, 0, stream>>>(frag, frag + (size_t)HW * CDIM, label, parts);

    finalize_kernel<<<1, 256, 0, stream>>>(parts, out);
}